// Round 6
// baseline (255.043 us; speedup 1.0000x reference)
//
#include <hip/hip_runtime.h>
#include <float.h>
#include <math.h>

#define NB 16
#define NN 577
#define NC 384
#define NH 6
#define ND 64
#define RPD2 2209
#define MTOT 9232
#define MPAD 9344
#define SCALE_ 0.125f
#define NEGBIG -3.0e38f
#define BSTRIDE 580
#define NKPAD 640

typedef __attribute__((ext_vector_type(8))) short bf16x8;
typedef __attribute__((ext_vector_type(4))) float f32x4;
typedef __attribute__((ext_vector_type(16))) float f32x16;
typedef unsigned short u16;

#define MFMA16(a, b, c) __builtin_amdgcn_mfma_f32_16x16x32_bf16(a, b, c, 0, 0, 0)
#define MFMA32(a, b, c) __builtin_amdgcn_mfma_f32_32x32x16_bf16(a, b, c, 0, 0, 0)

// workspace offsets in u16 units
#define SQA 3932160ull                    // 96*640*64
#define OFF_QH 0ull
#define OFF_QL SQA
#define OFF_KH (2ull * SQA)
#define OFF_KL (3ull * SQA)
#define OFF_VTH (4ull * SQA)
#define OFF_VTL (5ull * SQA)
#define OFF_XH (6ull * SQA)               // aliased as Oh after qkv
#define OFF_XL (6ull * SQA + 3588096ull)  // aliased as Ol
#define OFF_WQH (6ull * SQA + 2ull * 3588096ull)
#define OFF_WQL (OFF_WQH + 442368ull)
#define OFF_WPH (OFF_WQL + 442368ull)
#define OFF_WPL (OFF_WPH + 147456ull)
#define OFF_BT  (OFF_WPL + 147456ull)
#define OFF_PM  (OFF_BT + 2007960ull)     // u32 region, 8B-aligned

static __device__ __forceinline__ u16 f2bf(float f) {
  unsigned u = __float_as_uint(f);
  u += 0x7fff + ((u >> 16) & 1);
  return (u16)(u >> 16);
}
static __device__ __forceinline__ float bf2f(u16 h) {
  return __uint_as_float((unsigned)h << 16);
}
static __device__ __forceinline__ void split2(float v, u16& hi, u16& lo) {
  hi = f2bf(v);
  lo = f2bf(v - bf2f(hi));
}
static __device__ __forceinline__ void gload16(const void* g, void* l) {
  __builtin_amdgcn_global_load_lds(
      (const __attribute__((address_space(1))) void*)g,
      (__attribute__((address_space(3))) void*)l, 16, 0, 0);
}

// ---------------------------------------------------------------------------
// Split fp32 inputs into bf16 hi/lo pairs (x padded to 9344 rows).
// ---------------------------------------------------------------------------
__global__ __launch_bounds__(256) void split_inputs_k(
    const float* __restrict__ x, const float* __restrict__ wq,
    const float* __restrict__ wp, u16* __restrict__ ws)
{
  const int q = blockIdx.x * 256 + threadIdx.x;
  float4 v = {0.f, 0.f, 0.f, 0.f};
  u16 *dh, *dl;
  if (q < 897024) {
    if (q < 886272) v = ((const float4*)x)[q];
    dh = ws + OFF_XH + 4ull * q;
    dl = ws + OFF_XL + 4ull * q;
  } else if (q < 1007616) {
    int t = q - 897024;
    v = ((const float4*)wq)[t];
    dh = ws + OFF_WQH + 4ull * t;
    dl = ws + OFF_WQL + 4ull * t;
  } else {
    int t = q - 1007616;
    v = ((const float4*)wp)[t];
    dh = ws + OFF_WPH + 4ull * t;
    dl = ws + OFF_WPL + 4ull * t;
  }
  ushort4 hh, ll;
  split2(v.x, hh.x, ll.x);
  split2(v.y, hh.y, ll.y);
  split2(v.z, hh.z, ll.z);
  split2(v.w, hh.w, ll.w);
  *(ushort4*)dh = hh;
  *(ushort4*)dl = ll;
}

// ---------------------------------------------------------------------------
// Pack mask int32 -> bitmask.
// ---------------------------------------------------------------------------
__global__ __launch_bounds__(256) void pack_mask_k(const int* __restrict__ mask,
                                                   unsigned* __restrict__ pm)
{
  const int wid = (blockIdx.x * 256 + threadIdx.x) >> 6;
  const int lane = threadIdx.x & 63;
  if (wid >= MTOT) return;
  const int* mr = mask + (size_t)wid * NN;
#pragma unroll
  for (int c = 0; c < 10; ++c) {
    int k = c * 64 + lane;
    int v = (k < NN) ? mr[k] : 0;
    unsigned long long bal = __ballot(v != 0);
    if (lane == 0) pm[wid * 20 + 2 * c] = (unsigned)bal;
    if (lane == 1) pm[wid * 20 + 2 * c + 1] = (unsigned)(bal >> 32);
  }
}

// ---------------------------------------------------------------------------
// Bias table: tbl[h][q][kk] = rel_pos[h][rel_idx[(q-1)*576 + kk-1]] bf16.
// ---------------------------------------------------------------------------
__global__ __launch_bounds__(256) void bias_build_k(
    const float* __restrict__ rel_pos, const int* __restrict__ rel_idx,
    const int* __restrict__ patch, u16* __restrict__ tbl)
{
  const int q = blockIdx.x;
  const int h = blockIdx.y;
  const int pa = *patch;
  u16* row = tbl + ((size_t)h * NN + q) * BSTRIDE;
  for (int kk = threadIdx.x; kk < BSTRIDE; kk += 256) {
    float v = 0.f;
    if (pa && q >= 1 && kk >= 1 && kk < NN)
      v = rel_pos[h * RPD2 + rel_idx[(q - 1) * 576 + (kk - 1)]];
    row[kk] = f2bf(v);
  }
}

// ---------------------------------------------------------------------------
// QKV GEMM, split-bf16 16x16 MFMA with LDS staging (unchanged, proven).
// ---------------------------------------------------------------------------
__global__ __launch_bounds__(256, 3) void qkv_mfma_k(
    const u16* __restrict__ Xh, const u16* __restrict__ Xl,
    const u16* __restrict__ Wh, const u16* __restrict__ Wl,
    const float* __restrict__ bias, u16* __restrict__ ws)
{
  __shared__ u16 Ash[4096], Asl[4096];   // [128][32]
  __shared__ u16 Bsh[4096], Bsl[4096];

  const int tid = threadIdx.x;
  const int w = tid >> 6, l = tid & 63, lq = l & 15, lg = l >> 4;
  const int wm = (w >> 1) * 64, wn = (w & 1) * 64;
  const int mb = blockIdx.x * 128;
  const int rb = blockIdx.y * 128;
  const int r0 = rb + wn;
  const int soff = (l >> 2) * 384 + (l & 3) * 8;

  f32x4 acc[4][4];
#pragma unroll
  for (int nt = 0; nt < 4; ++nt) {
    float bv = bias[r0 + 16 * nt + lq];
#pragma unroll
    for (int mt = 0; mt < 4; ++mt) acc[mt][nt] = (f32x4){bv, bv, bv, bv};
  }

  for (int k0 = 0; k0 < 384; k0 += 32) {
    __syncthreads();
#pragma unroll
    for (int j = 0; j < 2; ++j) {
      const int tr = 32 * w + 16 * j;
      const size_t ga = (size_t)(mb + tr) * 384 + k0 + soff;
      const size_t gb = (size_t)(rb + tr) * 384 + k0 + soff;
      gload16(&Xh[ga], &Ash[tr * 32]);
      gload16(&Xl[ga], &Asl[tr * 32]);
      gload16(&Wh[gb], &Bsh[tr * 32]);
      gload16(&Wl[gb], &Bsl[tr * 32]);
    }
    __syncthreads();

    bf16x8 bhf[4], blf[4];
#pragma unroll
    for (int nt = 0; nt < 4; ++nt) {
      bhf[nt] = *(const bf16x8*)&Bsh[(wn + 16 * nt + lq) * 32 + 8 * lg];
      blf[nt] = *(const bf16x8*)&Bsl[(wn + 16 * nt + lq) * 32 + 8 * lg];
    }
#pragma unroll
    for (int mt = 0; mt < 4; ++mt) {
      bf16x8 ah = *(const bf16x8*)&Ash[(wm + 16 * mt + lq) * 32 + 8 * lg];
      bf16x8 al = *(const bf16x8*)&Asl[(wm + 16 * mt + lq) * 32 + 8 * lg];
#pragma unroll
      for (int nt = 0; nt < 4; ++nt) {
        acc[mt][nt] = MFMA16(ah, bhf[nt], acc[mt][nt]);
        acc[mt][nt] = MFMA16(ah, blf[nt], acc[mt][nt]);
        acc[mt][nt] = MFMA16(al, bhf[nt], acc[mt][nt]);
      }
    }
  }

  const int comp = rb / 384;
  const int h = ((rb % 384) + wn) >> 6;
#pragma unroll
  for (int mt = 0; mt < 4; ++mt)
#pragma unroll
    for (int r = 0; r < 4; ++r) {
      int m = mb + wm + 16 * mt + 4 * lg + r;
      if (m >= MTOT) continue;
      int bb = m / NN, nn = m - bb * NN;
      int bh = bb * NH + h;
#pragma unroll
      for (int nt = 0; nt < 4; ++nt) {
        int d = 16 * nt + lq;
        float v = acc[mt][nt][r];
        u16 hi, lo;
        if (comp == 0) {
          v *= SCALE_;
          split2(v, hi, lo);
          size_t a = ((size_t)bh * NKPAD + nn) * 64 + d;
          ws[OFF_QH + a] = hi;
          ws[OFF_QL + a] = lo;
        } else if (comp == 1) {
          split2(v, hi, lo);
          size_t a = ((size_t)bh * NKPAD + nn) * 64 + d;
          ws[OFF_KH + a] = hi;
          ws[OFF_KL + a] = lo;
        } else {
          split2(v, hi, lo);
          size_t a = ((size_t)bh * 64 + d) * NKPAD + nn;
          ws[OFF_VTH + a] = hi;
          ws[OFF_VTL + a] = lo;
        }
      }
    }
}

// ---------------------------------------------------------------------------
// Flash attention v4: 32x32x16 MFMA, 128 q-rows/block, wave-local softmax,
// P-lo dropped, XCD-swizzled flat grid (480 blocks).
// LDS: K hi/lo + V^T hi/lo [64][64] swizzled (32KB) + per-wave P-hi (16KB).
// ---------------------------------------------------------------------------
__global__ __launch_bounds__(256, 3) void attn_k(
    const u16* __restrict__ Qh, const u16* __restrict__ Ql,
    const u16* __restrict__ Kh, const u16* __restrict__ Kl,
    const u16* __restrict__ Vth, const u16* __restrict__ Vtl,
    const u16* __restrict__ btbl, const unsigned* __restrict__ pm,
    u16* __restrict__ Oh, u16* __restrict__ Ol)
{
  __shared__ u16 Kth[4096], Ktl[4096];   // [64 keys][64 d] 16B-slot swizzled
  __shared__ u16 Vsh[4096], Vsl[4096];   // [64 d][64 keys] swizzled
  __shared__ u16 Ps[4][2048];            // per-wave P-hi [32 q][64 k] swizzled

  const int tid = threadIdx.x;
  const int w = tid >> 6, l = tid & 63;
  const int qc = l & 31, hi = l >> 5;

  // XCD-aware decode: all 5 q-blocks of a (b,h) land on one XCD
  const int wg = blockIdx.x;
  const int xcd = wg & 7, slot = wg >> 3;
  const int bh = (slot / 5) * 8 + xcd;       // 0..95
  const int qb = slot % 5;
  const int b = bh / NH, h = bh % NH;
  const int q0 = qb * 128;

  const int q = q0 + 32 * w + qc;            // this lane's q column
  const int ln8 = l >> 3, lc8 = l & 7;
  const int koff = ln8 * 64 + ((lc8 ^ ln8) << 3);
  const int voff = ln8 * NKPAD + ((lc8 ^ ln8) << 3);

  // persistent Q fragments (B-operand): k = d = 16*st + 8*hi + j
  const size_t qrow = ((size_t)bh * NKPAD + q) * 64 + 8 * hi;
  bf16x8 qfh[4], qfl[4];
#pragma unroll
  for (int st = 0; st < 4; ++st) {
    qfh[st] = *(const bf16x8*)&Qh[qrow + 16 * st];
    qfl[st] = *(const bf16x8*)&Ql[qrow + 16 * st];
  }

  const bool qv = q < NN;
  const int gq = qv ? q : NN - 1;
  const unsigned* pmrow = pm + ((size_t)b * NN + gq) * 20;
  const size_t brow = ((size_t)h * NN + gq) * BSTRIDE;

  float m_reg = NEGBIG, l_reg = 0.f;
  f32x16 accO[2] = {};

  for (int ch = 0; ch < 10; ++ch) {
    const int kb = ch * 64;
    __syncthreads();   // prior chunk's LDS reads done
    {
      const size_t kgb = ((size_t)bh * NKPAD + kb + 16 * w) * 64 + koff;
      const size_t vgb = ((size_t)bh * 64 + 16 * w) * NKPAD + kb + voff;
      gload16(&Kh[kgb],              &Kth[(16 * w) * 64]);
      gload16(&Kh[kgb + 512],        &Kth[(16 * w + 8) * 64]);
      gload16(&Kl[kgb],              &Ktl[(16 * w) * 64]);
      gload16(&Kl[kgb + 512],        &Ktl[(16 * w + 8) * 64]);
      gload16(&Vth[vgb],             &Vsh[(16 * w) * 64]);
      gload16(&Vth[vgb + 8 * NKPAD], &Vsh[(16 * w + 8) * 64]);
      gload16(&Vtl[vgb],             &Vsl[(16 * w) * 64]);
      gload16(&Vtl[vgb + 8 * NKPAD], &Vsl[(16 * w + 8) * 64]);
    }
    // independent global work overlaps the staging drain
    unsigned long long m64 = (unsigned long long)pmrow[2 * ch] |
                             ((unsigned long long)pmrow[2 * ch + 1] << 32);
    f32x16 s[2];
#pragma unroll
    for (int kt = 0; kt < 2; ++kt) {
#pragma unroll
      for (int m = 0; m < 4; ++m) {
        int kkb = kb + 32 * kt + 8 * m + 4 * hi;
        ushort4 b4 = {0, 0, 0, 0};
        if (qv && kkb <= 576) b4 = *(const ushort4*)&btbl[brow + kkb];
        s[kt][4 * m + 0] = bf2f(b4.x);
        s[kt][4 * m + 1] = bf2f(b4.y);
        s[kt][4 * m + 2] = bf2f(b4.z);
        s[kt][4 * m + 3] = bf2f(b4.w);
      }
    }
    __syncthreads();   // K/V tiles ready

    // ---- S^T = K * Q^T (rows=keys, cols=q) ----
#pragma unroll
    for (int kt = 0; kt < 2; ++kt) {
      const int key = 32 * kt + qc;
      const int rbase = key * 64;
      const int sw = (key & 7);
#pragma unroll
      for (int st = 0; st < 4; ++st) {
        const int addr = rbase + (((2 * st + hi) ^ sw) << 3);
        bf16x8 ah = *(const bf16x8*)&Kth[addr];
        bf16x8 al = *(const bf16x8*)&Ktl[addr];
        s[kt] = MFMA32(ah, qfh[st], s[kt]);
        s[kt] = MFMA32(ah, qfl[st], s[kt]);
        s[kt] = MFMA32(al, qfh[st], s[kt]);
      }
    }

    // ---- mask + wave-local online softmax (lane col = q) ----
    float cmax = NEGBIG;
#pragma unroll
    for (int kt = 0; kt < 2; ++kt)
#pragma unroll
      for (int r = 0; r < 16; ++r) {
        int bit = 32 * kt + (r & 3) + 8 * (r >> 2) + 4 * hi;
        float v = ((m64 >> bit) & 1ull) ? s[kt][r] : NEGBIG;
        s[kt][r] = v;
        cmax = fmaxf(cmax, v);
      }
    cmax = fmaxf(cmax, __shfl_xor(cmax, 32));
    float m_new = fmaxf(m_reg, cmax);
    float fx = __expf(m_reg - m_new);
    float csum = 0.f;
#pragma unroll
    for (int kt = 0; kt < 2; ++kt)
#pragma unroll
      for (int m = 0; m < 4; ++m) {
        ushort4 pk;
        float e0 = __expf(s[kt][4 * m + 0] - m_new);
        float e1 = __expf(s[kt][4 * m + 1] - m_new);
        float e2 = __expf(s[kt][4 * m + 2] - m_new);
        float e3 = __expf(s[kt][4 * m + 3] - m_new);
        csum += e0 + e1 + e2 + e3;
        pk.x = f2bf(e0); pk.y = f2bf(e1); pk.z = f2bf(e2); pk.w = f2bf(e3);
        int saddr = qc * 64 + (((4 * kt + m) ^ (qc & 7)) << 3) + 4 * hi;
        *(ushort4*)&Ps[w][saddr] = pk;
      }
    csum += __shfl_xor(csum, 32);
    l_reg = l_reg * fx + csum;
    m_reg = m_new;

    // ---- rescale accO (fx per q-row via shfl) ----
#pragma unroll
    for (int r = 0; r < 16; ++r) {
      int qr = (r & 3) + 8 * (r >> 2) + 4 * hi;
      float fxr = __shfl(fx, 32 * w + qr);   // lane qr of this wave holds q=32w+qr... srcLane within wave
      accO[0][r] *= fxr;
      accO[1][r] *= fxr;
    }

    // ---- P fragments (wave-private) ----
    bf16x8 pa[4];
#pragma unroll
    for (int st = 0; st < 4; ++st) {
      int addr = qc * 64 + (((2 * st + hi) ^ (qc & 7)) << 3);
      pa[st] = *(const bf16x8*)&Ps[w][addr];
    }

    // ---- O += P * V ----
#pragma unroll
    for (int dt = 0; dt < 2; ++dt) {
      const int d = 32 * dt + qc;
      const int rbase = d * 64;
      const int sw = (d & 7);
#pragma unroll
      for (int st = 0; st < 4; ++st) {
        const int addr = rbase + (((2 * st + hi) ^ sw) << 3);
        bf16x8 vh = *(const bf16x8*)&Vsh[addr];
        bf16x8 vl = *(const bf16x8*)&Vsl[addr];
        accO[dt] = MFMA32(pa[st], vh, accO[dt]);
        accO[dt] = MFMA32(pa[st], vl, accO[dt]);
      }
    }
  }

  // ---- epilogue ----
  float il = 1.f / l_reg;
  float ilr[16];
#pragma unroll
  for (int r = 0; r < 16; ++r) {
    int qr = (r & 3) + 8 * (r >> 2) + 4 * hi;
    ilr[r] = __shfl(il, 32 * w + qr);
  }
#pragma unroll
  for (int dt = 0; dt < 2; ++dt)
#pragma unroll
    for (int r = 0; r < 16; ++r) {
      int gq2 = q0 + 32 * w + (r & 3) + 8 * (r >> 2) + 4 * hi;
      if (gq2 < NN) {
        float v = accO[dt][r] * ilr[r];
        u16 vh_, vl_;
        split2(v, vh_, vl_);
        size_t a = ((size_t)b * NN + gq2) * NC + h * 64 + 32 * dt + qc;
        Oh[a] = vh_;
        Ol[a] = vl_;
      }
    }
}

// ---------------------------------------------------------------------------
// Projection GEMM, split-bf16 16x16 MFMA with LDS staging (unchanged).
// ---------------------------------------------------------------------------
__global__ __launch_bounds__(256, 3) void proj_mfma_k(
    const u16* __restrict__ Ah, const u16* __restrict__ Al,
    const u16* __restrict__ Wh, const u16* __restrict__ Wl,
    const float* __restrict__ bias, float* __restrict__ out)
{
  __shared__ u16 Ash[4096], Asl[4096];
  __shared__ u16 Bsh[4096], Bsl[4096];

  const int tid = threadIdx.x;
  const int w = tid >> 6, l = tid & 63, lq = l & 15, lg = l >> 4;
  const int wm = (w >> 1) * 64, wn = (w & 1) * 64;
  const int mb = blockIdx.x * 128;
  const int rb = blockIdx.y * 128;
  const int r0 = rb + wn;
  const int soff = (l >> 2) * 384 + (l & 3) * 8;

  f32x4 acc[4][4];
#pragma unroll
  for (int nt = 0; nt < 4; ++nt) {
    float bv = bias[r0 + 16 * nt + lq];
#pragma unroll
    for (int mt = 0; mt < 4; ++mt) acc[mt][nt] = (f32x4){bv, bv, bv, bv};
  }

  for (int k0 = 0; k0 < 384; k0 += 32) {
    __syncthreads();
#pragma unroll
    for (int j = 0; j < 2; ++j) {
      const int tr = 32 * w + 16 * j;
      const size_t ga = (size_t)(mb + tr) * 384 + k0 + soff;
      const size_t gb = (size_t)(rb + tr) * 384 + k0 + soff;
      gload16(&Ah[ga], &Ash[tr * 32]);
      gload16(&Al[ga], &Asl[tr * 32]);
      gload16(&Wh[gb], &Bsh[tr * 32]);
      gload16(&Wl[gb], &Bsl[tr * 32]);
    }
    __syncthreads();

    bf16x8 bhf[4], blf[4];
#pragma unroll
    for (int nt = 0; nt < 4; ++nt) {
      bhf[nt] = *(const bf16x8*)&Bsh[(wn + 16 * nt + lq) * 32 + 8 * lg];
      blf[nt] = *(const bf16x8*)&Bsl[(wn + 16 * nt + lq) * 32 + 8 * lg];
    }
#pragma unroll
    for (int mt = 0; mt < 4; ++mt) {
      bf16x8 ah = *(const bf16x8*)&Ash[(wm + 16 * mt + lq) * 32 + 8 * lg];
      bf16x8 al = *(const bf16x8*)&Asl[(wm + 16 * mt + lq) * 32 + 8 * lg];
#pragma unroll
      for (int nt = 0; nt < 4; ++nt) {
        acc[mt][nt] = MFMA16(ah, bhf[nt], acc[mt][nt]);
        acc[mt][nt] = MFMA16(ah, blf[nt], acc[mt][nt]);
        acc[mt][nt] = MFMA16(al, bhf[nt], acc[mt][nt]);
      }
    }
  }

#pragma unroll
  for (int mt = 0; mt < 4; ++mt)
#pragma unroll
    for (int r = 0; r < 4; ++r) {
      int m = mb + wm + 16 * mt + 4 * lg + r;
      if (m >= MTOT) continue;
#pragma unroll
      for (int nt = 0; nt < 4; ++nt)
        out[(size_t)m * NC + r0 + 16 * nt + lq] = acc[mt][nt][r];
    }
}

// ---------------------------------------------------------------------------
extern "C" void kernel_launch(void* const* d_in, const int* in_sizes, int n_in,
                              void* d_out, int out_size, void* d_ws, size_t ws_size,
                              hipStream_t stream) {
  const float* x       = (const float*)d_in[0];
  const float* qkv_w   = (const float*)d_in[1];
  const float* qkv_b   = (const float*)d_in[2];
  const float* proj_w  = (const float*)d_in[3];
  const float* proj_b  = (const float*)d_in[4];
  const float* rel_pos = (const float*)d_in[5];
  const int*   rel_idx = (const int*)d_in[6];
  const int*   mask    = (const int*)d_in[7];
  const int*   patch   = (const int*)d_in[8];
  float* out = (float*)d_out;
  u16* W16 = (u16*)d_ws;

  unsigned* pmp = (unsigned*)(W16 + OFF_PM);
  u16* btblp = W16 + OFF_BT;

  split_inputs_k<<<4080, 256, 0, stream>>>(x, qkv_w, proj_w, W16);
  pack_mask_k<<<2308, 256, 0, stream>>>(mask, pmp);
  bias_build_k<<<dim3(NN, NH), 256, 0, stream>>>(rel_pos, rel_idx, patch, btblp);
  qkv_mfma_k<<<dim3(73, 9), 256, 0, stream>>>(
      W16 + OFF_XH, W16 + OFF_XL, W16 + OFF_WQH, W16 + OFF_WQL, qkv_b, W16);
  attn_k<<<480, 256, 0, stream>>>(
      W16 + OFF_QH, W16 + OFF_QL, W16 + OFF_KH, W16 + OFF_KL,
      W16 + OFF_VTH, W16 + OFF_VTL, btblp, pmp,
      W16 + OFF_XH, W16 + OFF_XL);
  proj_mfma_k<<<dim3(73, 3), 256, 0, stream>>>(
      W16 + OFF_XH, W16 + OFF_XL, W16 + OFF_WPH, W16 + OFF_WPL, proj_b, out);
}

// Round 7
// 171.150 us; speedup vs baseline: 1.4902x; 1.4902x over previous
//
#include <hip/hip_runtime.h>
#include <float.h>
#include <math.h>

#define NB 16
#define NN 577
#define NC 384
#define NH 6
#define ND 64
#define RPD2 2209
#define MTOT 9232
#define MPAD 9344
#define SCALE_ 0.125f
#define NEGBIG -3.0e38f
#define BSTRIDE 580
#define NKPAD 640

typedef __attribute__((ext_vector_type(8))) short bf16x8;
typedef __attribute__((ext_vector_type(4))) float f32x4;
typedef unsigned short u16;

#define MFMA16(a, b, c) __builtin_amdgcn_mfma_f32_16x16x32_bf16(a, b, c, 0, 0, 0)

// workspace offsets in u16 units
#define SQA 3932160ull                    // 96*640*64
#define OFF_QH 0ull
#define OFF_QL SQA
#define OFF_KH (2ull * SQA)
#define OFF_KL (3ull * SQA)
#define OFF_VTH (4ull * SQA)
#define OFF_VTL (5ull * SQA)
#define OFF_XH (6ull * SQA)               // aliased as Oh after qkv
#define OFF_XL (6ull * SQA + 3588096ull)  // aliased as Ol
#define OFF_WQH (6ull * SQA + 2ull * 3588096ull)
#define OFF_WQL (OFF_WQH + 442368ull)
#define OFF_WPH (OFF_WQL + 442368ull)
#define OFF_WPL (OFF_WPH + 147456ull)
#define OFF_BT  (OFF_WPL + 147456ull)
#define OFF_PM  (OFF_BT + 2007960ull)     // u32 region, 8B-aligned

static __device__ __forceinline__ u16 f2bf(float f) {
  unsigned u = __float_as_uint(f);
  u += 0x7fff + ((u >> 16) & 1);
  return (u16)(u >> 16);
}
static __device__ __forceinline__ float bf2f(u16 h) {
  return __uint_as_float((unsigned)h << 16);
}
static __device__ __forceinline__ void split2(float v, u16& hi, u16& lo) {
  hi = f2bf(v);
  lo = f2bf(v - bf2f(hi));
}
static __device__ __forceinline__ void gload16(const void* g, void* l) {
  __builtin_amdgcn_global_load_lds(
      (const __attribute__((address_space(1))) void*)g,
      (__attribute__((address_space(3))) void*)l, 16, 0, 0);
}

// ---------------------------------------------------------------------------
// Split fp32 inputs into bf16 hi/lo pairs (x padded to 9344 rows).
// ---------------------------------------------------------------------------
__global__ __launch_bounds__(256) void split_inputs_k(
    const float* __restrict__ x, const float* __restrict__ wq,
    const float* __restrict__ wp, u16* __restrict__ ws)
{
  const int q = blockIdx.x * 256 + threadIdx.x;
  float4 v = {0.f, 0.f, 0.f, 0.f};
  u16 *dh, *dl;
  if (q < 897024) {
    if (q < 886272) v = ((const float4*)x)[q];
    dh = ws + OFF_XH + 4ull * q;
    dl = ws + OFF_XL + 4ull * q;
  } else if (q < 1007616) {
    int t = q - 897024;
    v = ((const float4*)wq)[t];
    dh = ws + OFF_WQH + 4ull * t;
    dl = ws + OFF_WQL + 4ull * t;
  } else {
    int t = q - 1007616;
    v = ((const float4*)wp)[t];
    dh = ws + OFF_WPH + 4ull * t;
    dl = ws + OFF_WPL + 4ull * t;
  }
  ushort4 hh, ll;
  split2(v.x, hh.x, ll.x);
  split2(v.y, hh.y, ll.y);
  split2(v.z, hh.z, ll.z);
  split2(v.w, hh.w, ll.w);
  *(ushort4*)dh = hh;
  *(ushort4*)dl = ll;
}

// ---------------------------------------------------------------------------
// Pack mask int32 -> bitmask.
// ---------------------------------------------------------------------------
__global__ __launch_bounds__(256) void pack_mask_k(const int* __restrict__ mask,
                                                   unsigned* __restrict__ pm)
{
  const int wid = (blockIdx.x * 256 + threadIdx.x) >> 6;
  const int lane = threadIdx.x & 63;
  if (wid >= MTOT) return;
  const int* mr = mask + (size_t)wid * NN;
#pragma unroll
  for (int c = 0; c < 10; ++c) {
    int k = c * 64 + lane;
    int v = (k < NN) ? mr[k] : 0;
    unsigned long long bal = __ballot(v != 0);
    if (lane == 0) pm[wid * 20 + 2 * c] = (unsigned)bal;
    if (lane == 1) pm[wid * 20 + 2 * c + 1] = (unsigned)(bal >> 32);
  }
}

// ---------------------------------------------------------------------------
// Bias table: tbl[h][q][kk] = rel_pos[h][rel_idx[(q-1)*576 + kk-1]] bf16.
// ---------------------------------------------------------------------------
__global__ __launch_bounds__(256) void bias_build_k(
    const float* __restrict__ rel_pos, const int* __restrict__ rel_idx,
    const int* __restrict__ patch, u16* __restrict__ tbl)
{
  const int q = blockIdx.x;
  const int h = blockIdx.y;
  const int pa = *patch;
  u16* row = tbl + ((size_t)h * NN + q) * BSTRIDE;
  for (int kk = threadIdx.x; kk < BSTRIDE; kk += 256) {
    float v = 0.f;
    if (pa && q >= 1 && kk >= 1 && kk < NN)
      v = rel_pos[h * RPD2 + rel_idx[(q - 1) * 576 + (kk - 1)]];
    row[kk] = f2bf(v);
  }
}

// ---------------------------------------------------------------------------
// QKV GEMM, split-bf16 16x16 MFMA with LDS staging (proven).
// ---------------------------------------------------------------------------
__global__ __launch_bounds__(256, 3) void qkv_mfma_k(
    const u16* __restrict__ Xh, const u16* __restrict__ Xl,
    const u16* __restrict__ Wh, const u16* __restrict__ Wl,
    const float* __restrict__ bias, u16* __restrict__ ws)
{
  __shared__ u16 Ash[4096], Asl[4096];   // [128][32]
  __shared__ u16 Bsh[4096], Bsl[4096];

  const int tid = threadIdx.x;
  const int w = tid >> 6, l = tid & 63, lq = l & 15, lg = l >> 4;
  const int wm = (w >> 1) * 64, wn = (w & 1) * 64;
  const int mb = blockIdx.x * 128;
  const int rb = blockIdx.y * 128;
  const int r0 = rb + wn;
  const int soff = (l >> 2) * 384 + (l & 3) * 8;

  f32x4 acc[4][4];
#pragma unroll
  for (int nt = 0; nt < 4; ++nt) {
    float bv = bias[r0 + 16 * nt + lq];
#pragma unroll
    for (int mt = 0; mt < 4; ++mt) acc[mt][nt] = (f32x4){bv, bv, bv, bv};
  }

  for (int k0 = 0; k0 < 384; k0 += 32) {
    __syncthreads();
#pragma unroll
    for (int j = 0; j < 2; ++j) {
      const int tr = 32 * w + 16 * j;
      const size_t ga = (size_t)(mb + tr) * 384 + k0 + soff;
      const size_t gb = (size_t)(rb + tr) * 384 + k0 + soff;
      gload16(&Xh[ga], &Ash[tr * 32]);
      gload16(&Xl[ga], &Asl[tr * 32]);
      gload16(&Wh[gb], &Bsh[tr * 32]);
      gload16(&Wl[gb], &Bsl[tr * 32]);
    }
    __syncthreads();

    bf16x8 bhf[4], blf[4];
#pragma unroll
    for (int nt = 0; nt < 4; ++nt) {
      bhf[nt] = *(const bf16x8*)&Bsh[(wn + 16 * nt + lq) * 32 + 8 * lg];
      blf[nt] = *(const bf16x8*)&Bsl[(wn + 16 * nt + lq) * 32 + 8 * lg];
    }
#pragma unroll
    for (int mt = 0; mt < 4; ++mt) {
      bf16x8 ah = *(const bf16x8*)&Ash[(wm + 16 * mt + lq) * 32 + 8 * lg];
      bf16x8 al = *(const bf16x8*)&Asl[(wm + 16 * mt + lq) * 32 + 8 * lg];
#pragma unroll
      for (int nt = 0; nt < 4; ++nt) {
        acc[mt][nt] = MFMA16(ah, bhf[nt], acc[mt][nt]);
        acc[mt][nt] = MFMA16(ah, blf[nt], acc[mt][nt]);
        acc[mt][nt] = MFMA16(al, bhf[nt], acc[mt][nt]);
      }
    }
  }

  const int comp = rb / 384;
  const int h = ((rb % 384) + wn) >> 6;
#pragma unroll
  for (int mt = 0; mt < 4; ++mt)
#pragma unroll
    for (int r = 0; r < 4; ++r) {
      int m = mb + wm + 16 * mt + 4 * lg + r;
      if (m >= MTOT) continue;
      int bb = m / NN, nn = m - bb * NN;
      int bh = bb * NH + h;
#pragma unroll
      for (int nt = 0; nt < 4; ++nt) {
        int d = 16 * nt + lq;
        float v = acc[mt][nt][r];
        u16 hi, lo;
        if (comp == 0) {
          v *= SCALE_;
          split2(v, hi, lo);
          size_t a = ((size_t)bh * NKPAD + nn) * 64 + d;
          ws[OFF_QH + a] = hi;
          ws[OFF_QL + a] = lo;
        } else if (comp == 1) {
          split2(v, hi, lo);
          size_t a = ((size_t)bh * NKPAD + nn) * 64 + d;
          ws[OFF_KH + a] = hi;
          ws[OFF_KL + a] = lo;
        } else {
          split2(v, hi, lo);
          size_t a = ((size_t)bh * 64 + d) * NKPAD + nn;
          ws[OFF_VTH + a] = hi;
          ws[OFF_VTL + a] = lo;
        }
      }
    }
}

// ---------------------------------------------------------------------------
// Flash attention v5: round-5 structure + double-buffered K/V staging
// (one barrier per chunk, prefetch c+1 issued right after the barrier so the
// barrier's vmcnt drain waits on loads issued a full chunk earlier) + P-lo
// dropped (validated by round 6 absmax). LDS 72KB -> 2 blocks/CU.
// Grid: natural dim3(10, NH, NB) = 960 blocks (no XCD swizzle).
// ---------------------------------------------------------------------------
__global__ __launch_bounds__(256, 2) void attn_k(
    const u16* __restrict__ Qh, const u16* __restrict__ Ql,
    const u16* __restrict__ Kh, const u16* __restrict__ Kl,
    const u16* __restrict__ Vth, const u16* __restrict__ Vtl,
    const u16* __restrict__ btbl, const unsigned* __restrict__ pm,
    u16* __restrict__ Oh, u16* __restrict__ Ol)
{
  __shared__ u16 Kth[2][4096], Ktl[2][4096];  // [64 keys][64 d] swizzled
  __shared__ u16 Vsh[2][4096], Vsl[2][4096];  // [64 d][64 keys] swizzled
  __shared__ u16 Ph[4][1024];                 // per-wave P-hi [16 q][64 k]

  const int tid = threadIdx.x;
  const int w = tid >> 6, l = tid & 63, lq = l & 15, lg = l >> 4;
  const int q0 = blockIdx.x * 64;
  const int h = blockIdx.y, b = blockIdx.z;
  const int bh = b * NH + h;
  const int qrow = q0 + 16 * w + lq;
  const int swz = (lq & 7) << 3;
  const int ln8 = l >> 3, lc8 = l & 7;
  const int koff = ln8 * 64 + ((lc8 ^ ln8) << 3);
  const int voff = ln8 * NKPAD + ((lc8 ^ ln8) << 3);

  // stage chunk ch into buffer bf (8 x global_load_lds, 16B/lane)
#define STAGE(ch, bf)                                                        \
  {                                                                          \
    const int kb_ = (ch) * 64;                                               \
    const size_t kgb = ((size_t)bh * NKPAD + kb_ + 16 * w) * 64 + koff;      \
    const size_t vgb = ((size_t)bh * 64 + 16 * w) * NKPAD + kb_ + voff;      \
    gload16(&Kh[kgb],              &Kth[bf][(16 * w) * 64]);                 \
    gload16(&Kh[kgb + 512],        &Kth[bf][(16 * w + 8) * 64]);             \
    gload16(&Kl[kgb],              &Ktl[bf][(16 * w) * 64]);                 \
    gload16(&Kl[kgb + 512],        &Ktl[bf][(16 * w + 8) * 64]);             \
    gload16(&Vth[vgb],             &Vsh[bf][(16 * w) * 64]);                 \
    gload16(&Vth[vgb + 8 * NKPAD], &Vsh[bf][(16 * w + 8) * 64]);             \
    gload16(&Vtl[vgb],             &Vsl[bf][(16 * w) * 64]);                 \
    gload16(&Vtl[vgb + 8 * NKPAD], &Vsl[bf][(16 * w + 8) * 64]);             \
  }

  STAGE(0, 0);   // prologue prefetch

  // persistent Q fragments
  const size_t qbase = ((size_t)bh * NKPAD + qrow) * 64 + 8 * lg;
  bf16x8 qbh[2], qbl[2];
  qbh[0] = *(const bf16x8*)&Qh[qbase];
  qbh[1] = *(const bf16x8*)&Qh[qbase + 32];
  qbl[0] = *(const bf16x8*)&Ql[qbase];
  qbl[1] = *(const bf16x8*)&Ql[qbase + 32];

  const bool qv = qrow < NN;
  const int gqc = qv ? qrow : NN - 1;
  const unsigned* pmrow = pm + ((size_t)b * NN + gqc) * 20;
  const size_t brow = ((size_t)h * NN + gqc) * BSTRIDE;

  float m_reg = NEGBIG, l_reg = 0.f;
  f32x4 accO[4] = {};

  for (int ch = 0; ch < 10; ++ch) {
    const int kb = ch * 64;
    const int bf = ch & 1;
    // Single barrier per chunk: drains STAGE(ch) (issued a chunk ago) and
    // guarantees all waves finished reading buffer bf from chunk ch-2.
    __syncthreads();
    if (ch < 9) STAGE(ch + 1, bf ^ 1);

    unsigned long long m64 = (unsigned long long)pmrow[2 * ch] |
                             ((unsigned long long)pmrow[2 * ch + 1] << 32);
    f32x4 cinit[4];
#pragma unroll
    for (int t = 0; t < 4; ++t) {
      cinit[t] = (f32x4){0.f, 0.f, 0.f, 0.f};
      int kkb = kb + 16 * t + 4 * lg;
      if (qv && kkb <= 576) {
        ushort4 b4 = *(const ushort4*)&btbl[brow + kkb];
        cinit[t][0] = bf2f(b4.x); cinit[t][1] = bf2f(b4.y);
        cinit[t][2] = bf2f(b4.z); cinit[t][3] = bf2f(b4.w);
      }
    }

    // ---- S^T = K*Q^T ----
    float sv[4][4];
#pragma unroll
    for (int t = 0; t < 4; ++t) {
      f32x4 acc = cinit[t];
      const int ar = (16 * t + lq) * 64;
#pragma unroll
      for (int ks = 0; ks < 2; ++ks) {
        const int c = (8 * lg + 32 * ks) ^ swz;
        bf16x8 ah = *(const bf16x8*)&Kth[bf][ar + c];
        bf16x8 al = *(const bf16x8*)&Ktl[bf][ar + c];
        acc = MFMA16(ah, qbh[ks], acc);
        acc = MFMA16(ah, qbl[ks], acc);
        acc = MFMA16(al, qbh[ks], acc);
      }
      sv[t][0] = acc[0]; sv[t][1] = acc[1];
      sv[t][2] = acc[2]; sv[t][3] = acc[3];
    }

    // ---- mask + online softmax (lane q = qrow) ----
    float cmax = NEGBIG;
#pragma unroll
    for (int t = 0; t < 4; ++t)
#pragma unroll
      for (int r = 0; r < 4; ++r) {
        int kl = 16 * t + 4 * lg + r;
        float s = ((m64 >> kl) & 1ull) ? sv[t][r] : NEGBIG;
        sv[t][r] = s;
        cmax = fmaxf(cmax, s);
      }
    cmax = fmaxf(cmax, __shfl_xor(cmax, 16));
    cmax = fmaxf(cmax, __shfl_xor(cmax, 32));
    float m_new = fmaxf(m_reg, cmax);
    float fx = __expf(m_reg - m_new);
    float csum = 0.f;
    float ev[4][4];
#pragma unroll
    for (int t = 0; t < 4; ++t)
#pragma unroll
      for (int r = 0; r < 4; ++r) {
        float e = __expf(sv[t][r] - m_new);
        ev[t][r] = e;
        csum += e;
      }
    csum += __shfl_xor(csum, 16);
    csum += __shfl_xor(csum, 32);
    l_reg = l_reg * fx + csum;
    m_reg = m_new;

    // ---- P(hi only) -> per-wave LDS (swizzled) ----
#pragma unroll
    for (int t = 0; t < 4; ++t) {
      ushort4 ph;
      ph.x = f2bf(ev[t][0]);
      ph.y = f2bf(ev[t][1]);
      ph.z = f2bf(ev[t][2]);
      ph.w = f2bf(ev[t][3]);
      int c = (16 * t + 4 * lg) ^ swz;
      *(ushort4*)&Ph[w][lq * 64 + c] = ph;
    }

    // ---- rescale accO ----
    float fxr[4];
#pragma unroll
    for (int r = 0; r < 4; ++r) fxr[r] = __shfl(fx, 4 * lg + r);
#pragma unroll
    for (int t = 0; t < 4; ++t) {
      accO[t][0] *= fxr[0]; accO[t][1] *= fxr[1];
      accO[t][2] *= fxr[2]; accO[t][3] *= fxr[3];
    }

    // ---- P fragments (wave-private) ----
    bf16x8 pah[2];
#pragma unroll
    for (int ks = 0; ks < 2; ++ks) {
      int c = (8 * lg + 32 * ks) ^ swz;
      pah[ks] = *(const bf16x8*)&Ph[w][lq * 64 + c];
    }

    // ---- O += P V ----
#pragma unroll
    for (int t = 0; t < 4; ++t) {
      const int vr = (16 * t + lq) * 64;
#pragma unroll
      for (int ks = 0; ks < 2; ++ks) {
        const int c = (8 * lg + 32 * ks) ^ swz;
        bf16x8 vh = *(const bf16x8*)&Vsh[bf][vr + c];
        bf16x8 vl = *(const bf16x8*)&Vsl[bf][vr + c];
        accO[t] = MFMA16(pah[ks], vh, accO[t]);
        accO[t] = MFMA16(pah[ks], vl, accO[t]);
      }
    }
  }

  float il = 1.f / l_reg;
  float ilr[4];
#pragma unroll
  for (int r = 0; r < 4; ++r) ilr[r] = __shfl(il, 4 * lg + r);
#pragma unroll
  for (int t = 0; t < 4; ++t)
#pragma unroll
    for (int r = 0; r < 4; ++r) {
      int gq2 = q0 + 16 * w + 4 * lg + r;
      if (gq2 < NN) {
        float v = accO[t][r] * ilr[r];
        u16 hi, lo;
        split2(v, hi, lo);
        size_t a = ((size_t)b * NN + gq2) * NC + h * 64 + 16 * t + lq;
        Oh[a] = hi;
        Ol[a] = lo;
      }
    }
#undef STAGE
}

// ---------------------------------------------------------------------------
// Projection GEMM, split-bf16 16x16 MFMA with LDS staging (proven).
// ---------------------------------------------------------------------------
__global__ __launch_bounds__(256, 3) void proj_mfma_k(
    const u16* __restrict__ Ah, const u16* __restrict__ Al,
    const u16* __restrict__ Wh, const u16* __restrict__ Wl,
    const float* __restrict__ bias, float* __restrict__ out)
{
  __shared__ u16 Ash[4096], Asl[4096];
  __shared__ u16 Bsh[4096], Bsl[4096];

  const int tid = threadIdx.x;
  const int w = tid >> 6, l = tid & 63, lq = l & 15, lg = l >> 4;
  const int wm = (w >> 1) * 64, wn = (w & 1) * 64;
  const int mb = blockIdx.x * 128;
  const int rb = blockIdx.y * 128;
  const int r0 = rb + wn;
  const int soff = (l >> 2) * 384 + (l & 3) * 8;

  f32x4 acc[4][4];
#pragma unroll
  for (int nt = 0; nt < 4; ++nt) {
    float bv = bias[r0 + 16 * nt + lq];
#pragma unroll
    for (int mt = 0; mt < 4; ++mt) acc[mt][nt] = (f32x4){bv, bv, bv, bv};
  }

  for (int k0 = 0; k0 < 384; k0 += 32) {
    __syncthreads();
#pragma unroll
    for (int j = 0; j < 2; ++j) {
      const int tr = 32 * w + 16 * j;
      const size_t ga = (size_t)(mb + tr) * 384 + k0 + soff;
      const size_t gb = (size_t)(rb + tr) * 384 + k0 + soff;
      gload16(&Ah[ga], &Ash[tr * 32]);
      gload16(&Al[ga], &Asl[tr * 32]);
      gload16(&Wh[gb], &Bsh[tr * 32]);
      gload16(&Wl[gb], &Bsl[tr * 32]);
    }
    __syncthreads();

    bf16x8 bhf[4], blf[4];
#pragma unroll
    for (int nt = 0; nt < 4; ++nt) {
      bhf[nt] = *(const bf16x8*)&Bsh[(wn + 16 * nt + lq) * 32 + 8 * lg];
      blf[nt] = *(const bf16x8*)&Bsl[(wn + 16 * nt + lq) * 32 + 8 * lg];
    }
#pragma unroll
    for (int mt = 0; mt < 4; ++mt) {
      bf16x8 ah = *(const bf16x8*)&Ash[(wm + 16 * mt + lq) * 32 + 8 * lg];
      bf16x8 al = *(const bf16x8*)&Asl[(wm + 16 * mt + lq) * 32 + 8 * lg];
#pragma unroll
      for (int nt = 0; nt < 4; ++nt) {
        acc[mt][nt] = MFMA16(ah, bhf[nt], acc[mt][nt]);
        acc[mt][nt] = MFMA16(ah, blf[nt], acc[mt][nt]);
        acc[mt][nt] = MFMA16(al, bhf[nt], acc[mt][nt]);
      }
    }
  }

#pragma unroll
  for (int mt = 0; mt < 4; ++mt)
#pragma unroll
    for (int r = 0; r < 4; ++r) {
      int m = mb + wm + 16 * mt + 4 * lg + r;
      if (m >= MTOT) continue;
#pragma unroll
      for (int nt = 0; nt < 4; ++nt)
        out[(size_t)m * NC + r0 + 16 * nt + lq] = acc[mt][nt][r];
    }
}

// ---------------------------------------------------------------------------
extern "C" void kernel_launch(void* const* d_in, const int* in_sizes, int n_in,
                              void* d_out, int out_size, void* d_ws, size_t ws_size,
                              hipStream_t stream) {
  const float* x       = (const float*)d_in[0];
  const float* qkv_w   = (const float*)d_in[1];
  const float* qkv_b   = (const float*)d_in[2];
  const float* proj_w  = (const float*)d_in[3];
  const float* proj_b  = (const float*)d_in[4];
  const float* rel_pos = (const float*)d_in[5];
  const int*   rel_idx = (const int*)d_in[6];
  const int*   mask    = (const int*)d_in[7];
  const int*   patch   = (const int*)d_in[8];
  float* out = (float*)d_out;
  u16* W16 = (u16*)d_ws;

  unsigned* pmp = (unsigned*)(W16 + OFF_PM);
  u16* btblp = W16 + OFF_BT;

  split_inputs_k<<<4080, 256, 0, stream>>>(x, qkv_w, proj_w, W16);
  pack_mask_k<<<2308, 256, 0, stream>>>(mask, pmp);
  bias_build_k<<<dim3(NN, NH), 256, 0, stream>>>(rel_pos, rel_idx, patch, btblp);
  qkv_mfma_k<<<dim3(73, 9), 256, 0, stream>>>(
      W16 + OFF_XH, W16 + OFF_XL, W16 + OFF_WQH, W16 + OFF_WQL, qkv_b, W16);
  attn_k<<<dim3(10, NH, NB), 256, 0, stream>>>(
      W16 + OFF_QH, W16 + OFF_QL, W16 + OFF_KH, W16 + OFF_KL,
      W16 + OFF_VTH, W16 + OFF_VTL, btblp, pmp,
      W16 + OFF_XH, W16 + OFF_XL);
  proj_mfma_k<<<dim3(73, 3), 256, 0, stream>>>(
      W16 + OFF_XH, W16 + OFF_XL, W16 + OFF_WPH, W16 + OFF_WPL, proj_b, out);
}